// Round 4
// baseline (823.387 us; speedup 1.0000x reference)
//
#include <hip/hip_runtime.h>
#include <float.h>
#include <math.h>

#define NUM_T 8192
#define NUM_E 256
#define HID   7168

// ---------------------------------------------------------------------------
// Kernel 1: partial router logits, fp32 VALU GEMM — SGPR-X structure.
// grid = (NUM_T/32, SPLITK), block = 256 threads (4 waves), 4 blocks/CU.
// Wave wid owns tokens t0+8*wid..+7 (WAVE-UNIFORM -> X via s_load into
// SGPRs, used as the scalar operand of v_fma). Lane l owns experts
// 4l..4l+3. Per wave per k: exactly ONE ds_read_b128 (full 256-expert row,
// conflict-free). This removes X from the LDS pipe, which round-3 counters
// showed was the limiter (flat ~12cy/b128 issue cost: 4 instr/wave/k = 384
// cy/CU/k vs 256 VALU -> VALUBusy 60%).
// W LDS layout: ws[k][e ^ (k&28)] XOR swizzle (round-3 proven):
//  - staging writes 2-way conflicts only (free on gfx950)
//  - reads: lane l reads float4 at col 4*(l ^ (k>>2 & 7)); stored expert
//    = col ^ (k&28) = 4l..4l+3 for every k (swizzle only touches bits>=2).
// ---------------------------------------------------------------------------
template <int SPLITK>
__global__ __launch_bounds__(256, 4) void router_gemm(
    const float* __restrict__ X, const float* __restrict__ W,
    float* __restrict__ partial) {
  __shared__ float ws[32 * 256];  // [k][expert-swizzled], 32 KB

  const int tid = threadIdx.x;
  const int l = tid & 63;
  const int wid = __builtin_amdgcn_readfirstlane(tid >> 6);  // wave-uniform
  const int t0 = blockIdx.x * 32;
  const int kLen = HID / SPLITK;
  const int kStart = blockIdx.y * kLen;

  // Wave-uniform X row base (tokens t0+8*wid .. +7)
  const float* xrow = X + (size_t)(t0 + wid * 8) * HID + kStart;

  float4 acc[8];
#pragma unroll
  for (int t = 0; t < 8; ++t) acc[t] = make_float4(0.f, 0.f, 0.f, 0.f);

  const int we = tid >> 3;        // 0..31: W row within 32-row group
  const int wk = (tid & 7) << 2;  // 0..28 step 4: W col offset

  for (int kc = 0; kc < kLen; kc += 32) {
    const int k0 = kStart + kc;
    // Stage W chunk (256 x 32) transposed+swizzled -> ws[k][e ^ (k&28)]
#pragma unroll
    for (int r = 0; r < 8; ++r) {
      const int e = (r << 5) + we;
      const float4 v =
          *reinterpret_cast<const float4*>(W + (size_t)e * HID + k0 + wk);
      const int pc = e ^ wk;  // (wk+j)&28 == wk for j<4
      ws[(wk + 0) * 256 + pc] = v.x;
      ws[(wk + 1) * 256 + pc] = v.y;
      ws[(wk + 2) * 256 + pc] = v.z;
      ws[(wk + 3) * 256 + pc] = v.w;
    }
    __syncthreads();
#pragma unroll
    for (int k4 = 0; k4 < 32; k4 += 4) {
      const int q = k4 >> 2;               // 0..7
      const int colbase = (l ^ q) << 2;    // float index of this lane's f4
      // Wave-uniform X loads: 8 tokens x 4 k -> SGPRs via s_load_dwordx4
      float4 xq[8];
#pragma unroll
      for (int t = 0; t < 8; ++t)
        xq[t] = *reinterpret_cast<const float4*>(xrow + (size_t)t * HID + kc +
                                                 k4);
#pragma unroll
      for (int kk = 0; kk < 4; ++kk) {
        const float4 w =
            *reinterpret_cast<const float4*>(&ws[(k4 + kk) * 256 + colbase]);
#pragma unroll
        for (int t = 0; t < 8; ++t) {
          const float xv = (&xq[t].x)[kk];
          acc[t].x = fmaf(xv, w.x, acc[t].x);
          acc[t].y = fmaf(xv, w.y, acc[t].y);
          acc[t].z = fmaf(xv, w.z, acc[t].z);
          acc[t].w = fmaf(xv, w.w, acc[t].w);
        }
      }
    }
    __syncthreads();
  }

  float* out = partial + (size_t)blockIdx.y * NUM_T * NUM_E;
#pragma unroll
  for (int t = 0; t < 8; ++t) {
    *reinterpret_cast<float4*>(out + (size_t)(t0 + wid * 8 + t) * NUM_E +
                               (l << 2)) = acc[t];
  }
}

// ---------------------------------------------------------------------------
// Kernel 2: per-token selection, one wave per token (4 tokens / 256-thr block).
// Lane l owns experts 4l..4l+3 (all within group l/8). Reproduces jax
// lax.top_k tie-break (lower index first) at both group and expert level,
// including the flat-position ordering through group-rank.
// ---------------------------------------------------------------------------
__global__ __launch_bounds__(256) void router_select(
    const float* __restrict__ partial, int splitk,
    const float* __restrict__ bias, float* __restrict__ outIdx,
    float* __restrict__ outW) {
  const int lane = threadIdx.x & 63;
  const int t = blockIdx.x * 4 + (threadIdx.x >> 6);

  // Sum split-k partial logits
  float lg[4] = {0.f, 0.f, 0.f, 0.f};
  for (int s = 0; s < splitk; ++s) {
    const float4 p = *reinterpret_cast<const float4*>(
        partial + ((size_t)s * NUM_T + t) * NUM_E + lane * 4);
    lg[0] += p.x;
    lg[1] += p.y;
    lg[2] += p.z;
    lg[3] += p.w;
  }
  const float4 bv = *reinterpret_cast<const float4*>(bias + lane * 4);

  float sc[4], bs[4];
#pragma unroll
  for (int j = 0; j < 4; ++j) {
    sc[j] = 1.0f / (1.0f + expf(-lg[j]));  // sigmoid score (weights)
  }
  bs[0] = sc[0] + bv.x;
  bs[1] = sc[1] + bv.y;
  bs[2] = sc[2] + bv.z;
  bs[3] = sc[3] + bv.w;  // scores_for_choice

  // Group sums (8 groups of 32 experts = 8 lanes each)
  const int myg = lane >> 3;
  float gsum = bs[0] + bs[1] + bs[2] + bs[3];
#pragma unroll
  for (int d = 1; d < 8; d <<= 1) gsum += __shfl_xor(gsum, d);

  float gsv[8];
#pragma unroll
  for (int g = 0; g < 8; ++g) gsv[g] = __shfl(gsum, g * 8);

  // Top-4 groups, tie -> lower group index; record selection order (rank)
  unsigned selm = 0;
  int myrank = 0;
#pragma unroll
  for (int r = 0; r < 4; ++r) {
    int best = -1;
    float bvv = -FLT_MAX;
#pragma unroll
    for (int g = 0; g < 8; ++g) {
      if (!((selm >> g) & 1u) && gsv[g] > bvv) {
        bvv = gsv[g];
        best = g;
      }
    }
    selm |= 1u << best;
    if (best == myg) myrank = r;
  }
  const bool gsel = ((selm >> myg) & 1u) != 0u;

  float myv[4];
#pragma unroll
  for (int j = 0; j < 4; ++j) myv[j] = gsel ? bs[j] : -FLT_MAX;

  const int ebase = lane << 2;
  const int flatb = myrank * 32 + (lane & 7) * 4;  // jax flat position base

  float chosen_s = 0.f;
  int ex_out = 0;
  float ssum = 0.f;
  for (int r = 0; r < 8; ++r) {
    // local best among this lane's 4 candidates (value desc, flat asc)
    float v = -FLT_MAX;
    int fl = 1 << 30;
    int ex = 0;
    float s = 0.f;
#pragma unroll
    for (int j = 0; j < 4; ++j) {
      const bool better =
          (myv[j] > v) || (myv[j] == v && (flatb + j) < fl);
      if (better) {
        v = myv[j];
        fl = flatb + j;
        ex = ebase + j;
        s = sc[j];
      }
    }
    // wave butterfly argmax
#pragma unroll
    for (int d = 32; d > 0; d >>= 1) {
      const float v2 = __shfl_xor(v, d);
      const int fl2 = __shfl_xor(fl, d);
      const int ex2 = __shfl_xor(ex, d);
      const float s2 = __shfl_xor(s, d);
      if (v2 > v || (v2 == v && fl2 < fl)) {
        v = v2;
        fl = fl2;
        ex = ex2;
        s = s2;
      }
    }
    ssum += s;
    if (lane == r) {
      chosen_s = s;
      ex_out = ex;
    }
    if ((ex >> 2) == lane) myv[ex & 3] = -FLT_MAX;  // consume winner
  }

  if (lane < 8) {
    outIdx[t * 8 + lane] = (float)ex_out;
    outW[t * 8 + lane] = chosen_s / (ssum + 1e-20f) * 2.5f;
  }
}

extern "C" void kernel_launch(void* const* d_in, const int* in_sizes, int n_in,
                              void* d_out, int out_size, void* d_ws,
                              size_t ws_size, hipStream_t stream) {
  const float* X = (const float*)d_in[0];     // [8192, 7168]
  const float* W = (const float*)d_in[1];     // [256, 7168]
  const float* bias = (const float*)d_in[2];  // [256]
  float* partial = (float*)d_ws;

  const size_t slice = (size_t)NUM_T * NUM_E * sizeof(float);  // 8.4 MB
  int S;
  if (ws_size >= 4 * slice)
    S = 4;
  else if (ws_size >= 2 * slice)
    S = 2;
  else
    S = 1;

  dim3 grid(NUM_T / 32, S);
  if (S == 4)
    router_gemm<4><<<grid, 256, 0, stream>>>(X, W, partial);
  else if (S == 2)
    router_gemm<2><<<grid, 256, 0, stream>>>(X, W, partial);
  else
    router_gemm<1><<<grid, 256, 0, stream>>>(X, W, partial);

  float* outIdx = (float*)d_out;           // indices as exact float ints
  float* outW = outIdx + NUM_T * 8;        // weights
  router_select<<<NUM_T / 4, 256, 0, stream>>>(partial, S, bias, outIdx, outW);
}

// Round 5
// 711.471 us; speedup vs baseline: 1.1573x; 1.1573x over previous
//
#include <hip/hip_runtime.h>
#include <float.h>
#include <math.h>

#define NUM_T 8192
#define NUM_E 256
#define HID   7168

// ---------------------------------------------------------------------------
// Kernel 1: partial router logits, fp32 VALU GEMM — dot4 + global_load_lds.
// grid = (NUM_T/64, SPLITK), block = 128 threads (2 waves), 2 blocks/CU.
// Tile 64 tokens x 256 experts, k-chunk 32. Thread = 8 tokens x 16 experts.
// LDS holds k-CONTIGUOUS float4 fragments (4 k-values each) -> staging is
// pure global_load_lds width=16 (no transpose, no ds_writes, no VGPR trip).
// Inner product: acc[t][e] += dot4(xfrag, wfrag).
//   X slot(t,j) = 2048 + t*8 + (j ^ (t>>3))     (t<64, j<8)
//   W slot(e,j) =        e*8 + (j ^ ((e>>4)&7)) (e<256)
// Read conflicts: X reads -> 4 bank-groups x 16-lane broadcast (free);
// W reads -> 8 bank-groups x 2 addrs (2-way, free). DMA writes lane-ordered.
// Model: per CU-chunk LDS ~9.9k cy vs VALU 8.2k -> ~245 us wall (R3 was
// 14.2k LDS vs 8.2k VALU = 60% VALUBusy, model-validated).
// ---------------------------------------------------------------------------
template <int SPLITK>
__global__ __launch_bounds__(128, 1) void router_gemm(
    const float* __restrict__ X, const float* __restrict__ W,
    float* __restrict__ partial) {
  __shared__ float4 ls[2560];  // [0,2048): W slots, [2048,2560): X slots; 40KB

  const int tid = threadIdx.x;
  const int eg = tid & 15;       // expert group: experts eg*16 .. +15
  const int tg = tid >> 4;       // token group 0..7: tokens tg*8 .. +7
  const int E0 = eg << 4;
  const int T0 = tg << 3;
  const int t0 = blockIdx.x * 64;
  const int kLen = HID / SPLITK;
  const int kStart = blockIdx.y * kLen;

  // Per-thread staging pointers: slot s = it*128 + tid.
  const float* gptr[20];
#pragma unroll
  for (int it = 0; it < 20; ++it) {
    const int s = it * 128 + tid;
    if (s < 2048) {  // W slot
      const int e = s >> 3;
      const int j = (s & 7) ^ ((e >> 4) & 7);
      gptr[it] = W + (size_t)e * HID + kStart + 4 * j;
    } else {  // X slot
      const int s2 = s - 2048;
      const int t = s2 >> 3;
      const int j = (s2 & 7) ^ (t >> 3);
      gptr[it] = X + (size_t)(t0 + t) * HID + kStart + 4 * j;
    }
  }

  float acc[8][16];
#pragma unroll
  for (int i = 0; i < 8; ++i)
#pragma unroll
    for (int m = 0; m < 16; ++m) acc[i][m] = 0.f;

  for (int kc = 0; kc < kLen; kc += 32) {
    // Async stage: 20 x global_load_lds_dwordx4 per thread-slot
#pragma unroll
    for (int it = 0; it < 20; ++it) {
      __builtin_amdgcn_global_load_lds(
          (const __attribute__((address_space(1))) void*)gptr[it],
          (__attribute__((address_space(3))) void*)&ls[it * 128 + tid], 16, 0,
          0);
      gptr[it] += 32;
    }
    __syncthreads();  // compiler inserts vmcnt(0) drain

#pragma unroll 2
    for (int j = 0; j < 8; ++j) {
      float4 xf[8], wf[16];
#pragma unroll
      for (int i = 0; i < 8; ++i)
        xf[i] = ls[2048 + (T0 + i) * 8 + (j ^ tg)];
#pragma unroll
      for (int m = 0; m < 16; ++m)
        wf[m] = ls[(E0 + m) * 8 + (j ^ (eg & 7))];
#pragma unroll
      for (int i = 0; i < 8; ++i)
#pragma unroll
        for (int m = 0; m < 16; ++m) {
          float a = acc[i][m];
          a = fmaf(xf[i].x, wf[m].x, a);
          a = fmaf(xf[i].y, wf[m].y, a);
          a = fmaf(xf[i].z, wf[m].z, a);
          a = fmaf(xf[i].w, wf[m].w, a);
          acc[i][m] = a;
        }
    }
    __syncthreads();
  }

  float* out =
      partial + (size_t)blockIdx.y * NUM_T * NUM_E + (size_t)t0 * NUM_E;
#pragma unroll
  for (int i = 0; i < 8; ++i) {
#pragma unroll
    for (int m4 = 0; m4 < 4; ++m4) {
      float4 v = make_float4(acc[i][m4 * 4], acc[i][m4 * 4 + 1],
                             acc[i][m4 * 4 + 2], acc[i][m4 * 4 + 3]);
      *reinterpret_cast<float4*>(out + (size_t)(T0 + i) * NUM_E + E0 +
                                 m4 * 4) = v;
    }
  }
}

// ---------------------------------------------------------------------------
// Kernel 2: per-token selection, one wave per token (4 tokens / 256-thr block).
// Lane l owns experts 4l..4l+3. Reproduces jax lax.top_k tie-break (lower
// index first) at group and expert level, incl. flat-position order.
// ---------------------------------------------------------------------------
__global__ __launch_bounds__(256) void router_select(
    const float* __restrict__ partial, int splitk,
    const float* __restrict__ bias, float* __restrict__ outIdx,
    float* __restrict__ outW) {
  const int lane = threadIdx.x & 63;
  const int t = blockIdx.x * 4 + (threadIdx.x >> 6);

  // Sum split-k partial logits
  float lg[4] = {0.f, 0.f, 0.f, 0.f};
  for (int s = 0; s < splitk; ++s) {
    const float4 p = *reinterpret_cast<const float4*>(
        partial + ((size_t)s * NUM_T + t) * NUM_E + lane * 4);
    lg[0] += p.x;
    lg[1] += p.y;
    lg[2] += p.z;
    lg[3] += p.w;
  }
  const float4 bv = *reinterpret_cast<const float4*>(bias + lane * 4);

  float sc[4], bs[4];
#pragma unroll
  for (int j = 0; j < 4; ++j) {
    sc[j] = 1.0f / (1.0f + expf(-lg[j]));  // sigmoid score (weights)
  }
  bs[0] = sc[0] + bv.x;
  bs[1] = sc[1] + bv.y;
  bs[2] = sc[2] + bv.z;
  bs[3] = sc[3] + bv.w;  // scores_for_choice

  // Group sums (8 groups of 32 experts = 8 lanes each)
  const int myg = lane >> 3;
  float gsum = bs[0] + bs[1] + bs[2] + bs[3];
#pragma unroll
  for (int d = 1; d < 8; d <<= 1) gsum += __shfl_xor(gsum, d);

  float gsv[8];
#pragma unroll
  for (int g = 0; g < 8; ++g) gsv[g] = __shfl(gsum, g * 8);

  // Top-4 groups, tie -> lower group index; record selection order (rank)
  unsigned selm = 0;
  int myrank = 0;
#pragma unroll
  for (int r = 0; r < 4; ++r) {
    int best = -1;
    float bvv = -FLT_MAX;
#pragma unroll
    for (int g = 0; g < 8; ++g) {
      if (!((selm >> g) & 1u) && gsv[g] > bvv) {
        bvv = gsv[g];
        best = g;
      }
    }
    selm |= 1u << best;
    if (best == myg) myrank = r;
  }
  const bool gsel = ((selm >> myg) & 1u) != 0u;

  float myv[4];
#pragma unroll
  for (int j = 0; j < 4; ++j) myv[j] = gsel ? bs[j] : -FLT_MAX;

  const int ebase = lane << 2;
  const int flatb = myrank * 32 + (lane & 7) * 4;  // jax flat position base

  float chosen_s = 0.f;
  int ex_out = 0;
  float ssum = 0.f;
  for (int r = 0; r < 8; ++r) {
    // local best among this lane's 4 candidates (value desc, flat asc)
    float v = -FLT_MAX;
    int fl = 1 << 30;
    int ex = 0;
    float s = 0.f;
#pragma unroll
    for (int j = 0; j < 4; ++j) {
      const bool better =
          (myv[j] > v) || (myv[j] == v && (flatb + j) < fl);
      if (better) {
        v = myv[j];
        fl = flatb + j;
        ex = ebase + j;
        s = sc[j];
      }
    }
    // wave butterfly argmax
#pragma unroll
    for (int d = 32; d > 0; d >>= 1) {
      const float v2 = __shfl_xor(v, d);
      const int fl2 = __shfl_xor(fl, d);
      const int ex2 = __shfl_xor(ex, d);
      const float s2 = __shfl_xor(s, d);
      if (v2 > v || (v2 == v && fl2 < fl)) {
        v = v2;
        fl = fl2;
        ex = ex2;
        s = s2;
      }
    }
    ssum += s;
    if (lane == r) {
      chosen_s = s;
      ex_out = ex;
    }
    if ((ex >> 2) == lane) myv[ex & 3] = -FLT_MAX;  // consume winner
  }

  if (lane < 8) {
    outIdx[t * 8 + lane] = (float)ex_out;
    outW[t * 8 + lane] = chosen_s / (ssum + 1e-20f) * 2.5f;
  }
}

extern "C" void kernel_launch(void* const* d_in, const int* in_sizes, int n_in,
                              void* d_out, int out_size, void* d_ws,
                              size_t ws_size, hipStream_t stream) {
  const float* X = (const float*)d_in[0];     // [8192, 7168]
  const float* W = (const float*)d_in[1];     // [256, 7168]
  const float* bias = (const float*)d_in[2];  // [256]
  float* partial = (float*)d_ws;

  const size_t slice = (size_t)NUM_T * NUM_E * sizeof(float);  // 8.4 MB
  int S;
  if (ws_size >= 4 * slice)
    S = 4;
  else if (ws_size >= 2 * slice)
    S = 2;
  else
    S = 1;

  dim3 grid(NUM_T / 64, S);
  if (S == 4)
    router_gemm<4><<<grid, 128, 0, stream>>>(X, W, partial);
  else if (S == 2)
    router_gemm<2><<<grid, 128, 0, stream>>>(X, W, partial);
  else
    router_gemm<1><<<grid, 128, 0, stream>>>(X, W, partial);

  float* outIdx = (float*)d_out;           // indices as exact float ints
  float* outW = outIdx + NUM_T * 8;        // weights
  router_select<<<NUM_T / 4, 256, 0, stream>>>(partial, S, bias, outIdx, outW);
}